// Round 2
// baseline (484.331 us; speedup 1.0000x reference)
//
#include <hip/hip_runtime.h>
#include <math.h>

#define N_TRAIN 400000
#define DIMS    27
#define BQ      512
#define NCLS    11
#define KNN     3
#define G1      1024   // pass-1 blocks
#define PPB     391    // ceil(N_TRAIN / G1)
#define T1      128    // pass-1 threads per block (2 waves)
#define T2      256    // pass-2 threads
#define PREP_PB 1563   // ceil(N_TRAIN/256) blocks for the xn part of k_prep

// ---------------- scale = max(|train|, axis=0) ----------------
__global__ __launch_bounds__(256) void k_scale(const float* __restrict__ train,
                                               unsigned* __restrict__ scale_u) {
    float m[DIMS];
#pragma unroll
    for (int d = 0; d < DIMS; ++d) m[d] = 0.f;
    int tid = threadIdx.x;
    int stride = gridDim.x * 256;
    for (int r = blockIdx.x * 256 + tid; r < N_TRAIN; r += stride) {
        const float* row = train + (size_t)r * DIMS;
#pragma unroll
        for (int d = 0; d < DIMS; ++d) m[d] = fmaxf(m[d], fabsf(row[d]));
    }
#pragma unroll
    for (int d = 0; d < DIMS; ++d) {
#pragma unroll
        for (int off = 32; off >= 1; off >>= 1)
            m[d] = fmaxf(m[d], __shfl_down(m[d], off, 64));
    }
    __shared__ float sm[4 * DIMS];
    int lane = tid & 63, w = tid >> 6;
    if (lane == 0) {
#pragma unroll
        for (int d = 0; d < DIMS; ++d) sm[w * DIMS + d] = m[d];
    }
    __syncthreads();
    if (tid < DIMS) {
        float v = fmaxf(fmaxf(sm[tid], sm[DIMS + tid]),
                        fmaxf(sm[2 * DIMS + tid], sm[3 * DIMS + tid]));
        atomicMax(&scale_u[tid], __float_as_uint(v)); // values >= 0: uint order == float order
    }
}

// ---------------- prep: xn[p] = ||x_s||^2 ; qw[q][d] = q_s[d]/s_d, qw[q][27] = ||q_s||^2 ----
__global__ __launch_bounds__(256) void k_prep(const float* __restrict__ train,
                                              const float* __restrict__ query,
                                              const unsigned* __restrict__ scale_u,
                                              float* __restrict__ qw,
                                              float* __restrict__ xn) {
    __shared__ float s_inv[DIMS];
    int tid = threadIdx.x;
    if (tid < DIMS) {
        float sc = __uint_as_float(scale_u[tid]);
        s_inv[tid] = (sc != 0.f) ? 1.f / sc : 0.f;  // divide_no_nan
    }
    __syncthreads();
    int b = blockIdx.x;
    if (b < PREP_PB) {
        int p = b * 256 + tid;
        if (p < N_TRAIN) {
            const float* r = train + (size_t)p * DIMS;
            float s2 = 0.f;
#pragma unroll
            for (int d = 0; d < DIMS; ++d) {
                float v = r[d] * s_inv[d];
                s2 = fmaf(v, v, s2);
            }
            xn[p] = s2;
        }
    } else {
        int q = (b - PREP_PB) * 256 + tid;
        if (q < BQ) {
            const float* r = query + (size_t)q * DIMS;
            float* o = qw + (size_t)q * 28;
            float s2 = 0.f;
#pragma unroll
            for (int d = 0; d < DIMS; ++d) {
                float inv = s_inv[d];
                float v = r[d] * inv;          // q_s
                s2 = fmaf(v, v, s2);
                o[d] = v * inv;                // fold second 1/s: dot(q_s,x_s) = sum qw*x_raw
            }
            o[27] = s2;                        // qn
        }
    }
}

// ---------------- pass 1: per-chunk top-3 per query ----------------
// No LDS, no barriers in the hot loop. Point data read at wave-uniform
// addresses (raw train rows) -> scalar-cache / single-line L1 traffic.
__global__ __launch_bounds__(T1, 2) void k_pass1(const float* __restrict__ train,
                                                 const float* __restrict__ xn,
                                                 const float* __restrict__ qwm,
                                                 float* __restrict__ cand_d,
                                                 int* __restrict__ cand_i) {
    int tid = threadIdx.x;
    // 4 queries per thread, resident in VGPRs (launch_bounds(128,2) -> 256 VGPR cap)
    float q[4][DIMS], qn4[4];
#pragma unroll
    for (int j = 0; j < 4; ++j) {
        const float* r = qwm + (size_t)(tid + j * T1) * 28;
#pragma unroll
        for (int d = 0; d < DIMS; ++d) q[j][d] = r[d];
        qn4[j] = r[27];
    }
    float bd[4][KNN];
    int   bi[4][KNN];
#pragma unroll
    for (int j = 0; j < 4; ++j)
#pragma unroll
        for (int k = 0; k < KNN; ++k) { bd[j][k] = 3.4e38f; bi[j][k] = 0; }

    int p0 = blockIdx.x * PPB;
    int pe = min(p0 + PPB, N_TRAIN);
    const float* xp = train + (size_t)p0 * DIMS;

    for (int p = p0; p < pe; ++p, xp += DIMS) {
        float x[DIMS];
#pragma unroll
        for (int d = 0; d < DIMS; ++d) x[d] = xp[d];   // wave-uniform loads
        float pxn = xn[p];
#pragma unroll
        for (int j = 0; j < 4; ++j) {
            float dot = 0.f;
#pragma unroll
            for (int d = 0; d < DIMS; ++d) dot = fmaf(q[j][d], x[d], dot);
            float d2 = fmaf(-2.f, dot, qn4[j] + pxn);
            if (d2 < bd[j][2]) { // strict <: earlier (lower) index wins ties
                if (d2 < bd[j][1]) {
                    bd[j][2] = bd[j][1]; bi[j][2] = bi[j][1];
                    if (d2 < bd[j][0]) {
                        bd[j][1] = bd[j][0]; bi[j][1] = bi[j][0];
                        bd[j][0] = d2; bi[j][0] = p;
                    } else { bd[j][1] = d2; bi[j][1] = p; }
                } else { bd[j][2] = d2; bi[j][2] = p; }
            }
        }
    }

    int g = blockIdx.x;
#pragma unroll
    for (int j = 0; j < 4; ++j) {
        int qq = tid + j * T1;
        size_t off = (size_t)qq * (G1 * KNN) + (size_t)g * KNN;
#pragma unroll
        for (int k = 0; k < KNN; ++k) { cand_d[off + k] = bd[j][k]; cand_i[off + k] = bi[j][k]; }
    }
}

// lexicographic (d, i) insert into sorted triple — matches top_k tie-breaking
__device__ inline void insert3(float d, int i, float* bd, int* bi) {
    if (d < bd[2] || (d == bd[2] && i < bi[2])) {
        if (d < bd[1] || (d == bd[1] && i < bi[1])) {
            bd[2] = bd[1]; bi[2] = bi[1];
            if (d < bd[0] || (d == bd[0] && i < bi[0])) {
                bd[1] = bd[0]; bi[1] = bi[0];
                bd[0] = d; bi[0] = i;
            } else { bd[1] = d; bi[1] = i; }
        } else { bd[2] = d; bi[2] = i; }
    }
}

// ---------------- pass 2: merge + vote ----------------
__global__ __launch_bounds__(T2) void k_pass2(const float* __restrict__ cand_d,
                                              const int* __restrict__ cand_i,
                                              const float* __restrict__ labels,
                                              float* __restrict__ out) {
    int q = blockIdx.x, tid = threadIdx.x;
    const float* cd = cand_d + (size_t)q * (G1 * KNN);
    const int*   ci = cand_i + (size_t)q * (G1 * KNN);
    float bd[KNN] = {3.4e38f, 3.4e38f, 3.4e38f};
    int   bi[KNN] = {0x7fffffff, 0x7fffffff, 0x7fffffff};
    for (int c = tid; c < G1 * KNN; c += T2) insert3(cd[c], ci[c], bd, bi);

    __shared__ float sd[T2][KNN];
    __shared__ int   si[T2][KNN];
#pragma unroll
    for (int k = 0; k < KNN; ++k) { sd[tid][k] = bd[k]; si[tid][k] = bi[k]; }
    __syncthreads();
    for (int s = T2 / 2; s > 0; s >>= 1) {
        if (tid < s) {
#pragma unroll
            for (int k = 0; k < KNN; ++k) insert3(sd[tid + s][k], si[tid + s][k], bd, bi);
#pragma unroll
            for (int k = 0; k < KNN; ++k) { sd[tid][k] = bd[k]; si[tid][k] = bi[k]; }
        }
        __syncthreads();
    }

    if (tid == 0) {
        float kd[KNN];
#pragma unroll
        for (int k = 0; k < KNN; ++k) kd[k] = sqrtf(fmaxf(bd[k], 0.f));
        float lab[KNN][NCLS];
#pragma unroll
        for (int k = 0; k < KNN; ++k) {
            const float* lr = labels + (size_t)bi[k] * NCLS;
#pragma unroll
            for (int c = 0; c < NCLS; ++c) lab[k][c] = lr[c];
        }
        float votes[NCLS];
#pragma unroll
        for (int c = 0; c < NCLS; ++c) votes[c] = 0.f;
#pragma unroll
        for (int k = 0; k < KNN; ++k) {
            float ks = (kd[k] == 0.f) ? 1.f : kd[k];
#pragma unroll
            for (int c = 0; c < NCLS; ++c) votes[c] += lab[k][c] / ks;
        }
        int best = 0; float bv = votes[0];
#pragma unroll
        for (int c = 1; c < NCLS; ++c) { if (votes[c] > bv) { bv = votes[c]; best = c; } }
        bool zero_hit = (kd[0] == 0.f);
#pragma unroll
        for (int k = 0; k < KNN; ++k) out[(size_t)q * KNN + k] = kd[k];
        float* ro = out + (size_t)BQ * KNN + (size_t)q * NCLS;
#pragma unroll
        for (int c = 0; c < NCLS; ++c)
            ro[c] = zero_hit ? lab[0][c] : ((c == best) ? 1.f : 0.f);
    }
}

extern "C" void kernel_launch(void* const* d_in, const int* in_sizes, int n_in,
                              void* d_out, int out_size, void* d_ws, size_t ws_size,
                              hipStream_t stream) {
    const float* query  = (const float*)d_in[0];
    const float* train  = (const float*)d_in[1];
    const float* labels = (const float*)d_in[2];
    float* out = (float*)d_out;

    // ws layout (all 128B-aligned):
    //   [0)        scale_u: 32 u32 (128 B)
    //   [128)      qw: 512*28 f32 (57344 B)   row = {qw[0..26], qn}
    //   [57472)    xn: 400000 f32 (1.6e6 B)
    //   [1657472)  cand_d: 512*1024*3 f32 (6291456 B)
    //   [7948928)  cand_i: 512*1024*3 i32 (6291456 B)   total ~14.24 MB
    char* ws = (char*)d_ws;
    unsigned* scale_u = (unsigned*)ws;
    float* qw     = (float*)(ws + 128);
    float* xn     = (float*)(ws + 57472);
    float* cand_d = (float*)(ws + 1657472);
    int*   cand_i = (int*)(ws + 7948928);

    hipMemsetAsync(ws, 0, 128, stream);  // zero scale accumulators
    k_scale<<<256, 256, 0, stream>>>(train, scale_u);
    k_prep<<<PREP_PB + 2, 256, 0, stream>>>(train, query, scale_u, qw, xn);
    k_pass1<<<G1, T1, 0, stream>>>(train, xn, qw, cand_d, cand_i);
    k_pass2<<<BQ, T2, 0, stream>>>(cand_d, cand_i, labels, out);
}

// Round 3
// 304.421 us; speedup vs baseline: 1.5910x; 1.5910x over previous
//
#include <hip/hip_runtime.h>
#include <math.h>

#define N_TRAIN 400000
#define DIMS    27
#define BQ      512
#define NCLS    11
#define KNN     3
#define G1      1024   // pass-1 blocks
#define PPB     391    // ceil(N_TRAIN / G1)
#define T1      256    // pass-1 threads per block (4 waves)
#define QPT     2      // queries per thread (T1*QPT == BQ)
#define SPTS    128    // points staged in LDS per iteration
#define T2      256    // pass-2 threads
#define SB      512    // k_scale blocks
#define SROWS   128    // k_scale rows per tile

// ---------------- scale = max(|train|, axis=0), coalesced via LDS staging ----------------
__global__ __launch_bounds__(256) void k_scale(const float* __restrict__ train,
                                               unsigned* __restrict__ scale_u) {
    __shared__ float st[SROWS * DIMS];
    __shared__ float sp[243];           // 27 cols x 9 row-groups
    int tid = threadIdx.x;
    int rpb = (N_TRAIN + SB - 1) / SB;  // 782 rows per block
    int r0 = blockIdx.x * rpb;
    int r1 = min(r0 + rpb, N_TRAIN);
    int c  = tid % DIMS;                // column owned in reduce phase
    int rr = tid / DIMS;                // row-group (0..8 for tid<243)
    float m = 0.f;
    for (int base = r0; base < r1; base += SROWS) {
        int cnt = min(SROWS, r1 - base);
        int tot = cnt * DIMS;
        const float* src = train + (size_t)base * DIMS;
        for (int i = tid; i < tot; i += 256) st[i] = src[i];   // flat coalesced
        __syncthreads();
        if (tid < 243) {
            for (int r = rr; r < cnt; r += 9)
                m = fmaxf(m, fabsf(st[r * DIMS + c]));
        }
        __syncthreads();
    }
    if (tid < 243) sp[tid] = m;
    __syncthreads();
    if (tid < DIMS) {
        float v = 0.f;
#pragma unroll
        for (int g = 0; g < 9; ++g) v = fmaxf(v, sp[g * DIMS + tid]);
        atomicMax(&scale_u[tid], __float_as_uint(v)); // values >= 0: uint order == float order
    }
}

// ---------------- scaled queries + query norms ----------------
__global__ __launch_bounds__(256) void k_qprep(const float* __restrict__ query,
                                               const unsigned* __restrict__ scale_u,
                                               float* __restrict__ qs) {
    int q = blockIdx.x * 256 + threadIdx.x;
    if (q >= BQ) return;
    const float* row = query + (size_t)q * DIMS;
    float* o = qs + (size_t)q * 28;
    float s2 = 0.f;
#pragma unroll
    for (int d = 0; d < DIMS; ++d) {
        float sc = __uint_as_float(scale_u[d]);
        float inv = (sc != 0.f) ? 1.f / sc : 0.f;   // divide_no_nan
        float v = row[d] * inv;
        o[d] = v;
        s2 = fmaf(v, v, s2);
    }
    o[27] = s2;
}

// ---------------- pass 1: per-chunk top-3 per query ----------------
// R1 structure (LDS-staged scaled points, broadcast ds_read_b128) with
// QPT=2 queries/thread so the query array stays in VGPRs (no scratch spill).
__global__ __launch_bounds__(T1, 2) void k_pass1(const float* __restrict__ train,
                                                 const unsigned* __restrict__ scale_u,
                                                 const float* __restrict__ qs,
                                                 float* __restrict__ cand_d,
                                                 int* __restrict__ cand_i) {
    __shared__ float s_inv[DIMS];
    __shared__ float s_pts[SPTS * 28]; // [point][0..26]=scaled dims, [27]=||x||^2
    int tid = threadIdx.x;
    if (tid < DIMS) {
        float sc = __uint_as_float(scale_u[tid]);
        s_inv[tid] = (sc != 0.f) ? 1.f / sc : 0.f;
    }
    float q[QPT][DIMS], qn[QPT];
#pragma unroll
    for (int j = 0; j < QPT; ++j) {
        const float* r = qs + (size_t)(j * T1 + tid) * 28;
#pragma unroll
        for (int d = 0; d < DIMS; ++d) q[j][d] = r[d];
        qn[j] = r[27];
    }
    float bd[QPT][KNN];
    int   bi[QPT][KNN];
#pragma unroll
    for (int j = 0; j < QPT; ++j)
#pragma unroll
        for (int k = 0; k < KNN; ++k) { bd[j][k] = 3.4e38f; bi[j][k] = 0; }

    int p0 = blockIdx.x * PPB;
    int pe = min(p0 + PPB, N_TRAIN);
    __syncthreads(); // s_inv ready

    for (int base = p0; base < pe; base += SPTS) {
        int cnt = min(SPTS, pe - base);
        int tot = cnt * DIMS;
        const float* src = train + (size_t)base * DIMS; // contiguous rows -> flat coalesced copy
        for (int i = tid; i < tot; i += T1) {
            int row = i / DIMS;
            int col = i - row * DIMS;
            s_pts[row * 28 + col] = src[i] * s_inv[col];
        }
        __syncthreads();
        for (int p = tid; p < cnt; p += T1) {
            float s2 = 0.f;
#pragma unroll
            for (int d = 0; d < DIMS; ++d) { float v = s_pts[p * 28 + d]; s2 = fmaf(v, v, s2); }
            s_pts[p * 28 + 27] = s2;
        }
        __syncthreads();

        for (int p = 0; p < cnt; ++p) {
            float px[28];
            const float4* rr = (const float4*)(s_pts + p * 28); // broadcast: all lanes same addr
#pragma unroll
            for (int k = 0; k < 7; ++k) {
                float4 v = rr[k];
                px[4 * k + 0] = v.x; px[4 * k + 1] = v.y;
                px[4 * k + 2] = v.z; px[4 * k + 3] = v.w;
            }
            float xnp = px[27];
            int gidx = base + p;
#pragma unroll
            for (int j = 0; j < QPT; ++j) {
                float dot = 0.f;
#pragma unroll
                for (int d = 0; d < DIMS; ++d) dot = fmaf(q[j][d], px[d], dot);
                float d2 = fmaf(-2.f, dot, qn[j] + xnp);
                if (d2 < bd[j][2]) { // strict <: earlier (lower) index wins ties
                    if (d2 < bd[j][1]) {
                        bd[j][2] = bd[j][1]; bi[j][2] = bi[j][1];
                        if (d2 < bd[j][0]) {
                            bd[j][1] = bd[j][0]; bi[j][1] = bi[j][0];
                            bd[j][0] = d2; bi[j][0] = gidx;
                        } else { bd[j][1] = d2; bi[j][1] = gidx; }
                    } else { bd[j][2] = d2; bi[j][2] = gidx; }
                }
            }
        }
        __syncthreads();
    }

    int g = blockIdx.x;
#pragma unroll
    for (int j = 0; j < QPT; ++j) {
        int qq = j * T1 + tid;
        size_t off = (size_t)qq * (G1 * KNN) + (size_t)g * KNN;
#pragma unroll
        for (int k = 0; k < KNN; ++k) { cand_d[off + k] = bd[j][k]; cand_i[off + k] = bi[j][k]; }
    }
}

// lexicographic (d, i) insert into sorted triple — matches top_k tie-breaking
__device__ inline void insert3(float d, int i, float* bd, int* bi) {
    if (d < bd[2] || (d == bd[2] && i < bi[2])) {
        if (d < bd[1] || (d == bd[1] && i < bi[1])) {
            bd[2] = bd[1]; bi[2] = bi[1];
            if (d < bd[0] || (d == bd[0] && i < bi[0])) {
                bd[1] = bd[0]; bi[1] = bi[0];
                bd[0] = d; bi[0] = i;
            } else { bd[1] = d; bi[1] = i; }
        } else { bd[2] = d; bi[2] = i; }
    }
}

// ---------------- pass 2: merge + vote ----------------
__global__ __launch_bounds__(T2) void k_pass2(const float* __restrict__ cand_d,
                                              const int* __restrict__ cand_i,
                                              const float* __restrict__ labels,
                                              float* __restrict__ out) {
    int q = blockIdx.x, tid = threadIdx.x;
    const float* cd = cand_d + (size_t)q * (G1 * KNN);
    const int*   ci = cand_i + (size_t)q * (G1 * KNN);
    float bd[KNN] = {3.4e38f, 3.4e38f, 3.4e38f};
    int   bi[KNN] = {0x7fffffff, 0x7fffffff, 0x7fffffff};
    for (int c = tid; c < G1 * KNN; c += T2) insert3(cd[c], ci[c], bd, bi);

    __shared__ float sd[T2][KNN];
    __shared__ int   si[T2][KNN];
#pragma unroll
    for (int k = 0; k < KNN; ++k) { sd[tid][k] = bd[k]; si[tid][k] = bi[k]; }
    __syncthreads();
    for (int s = T2 / 2; s > 0; s >>= 1) {
        if (tid < s) {
#pragma unroll
            for (int k = 0; k < KNN; ++k) insert3(sd[tid + s][k], si[tid + s][k], bd, bi);
#pragma unroll
            for (int k = 0; k < KNN; ++k) { sd[tid][k] = bd[k]; si[tid][k] = bi[k]; }
        }
        __syncthreads();
    }

    if (tid == 0) {
        float kd[KNN];
#pragma unroll
        for (int k = 0; k < KNN; ++k) kd[k] = sqrtf(fmaxf(bd[k], 0.f));
        float lab[KNN][NCLS];
#pragma unroll
        for (int k = 0; k < KNN; ++k) {
            const float* lr = labels + (size_t)bi[k] * NCLS;
#pragma unroll
            for (int c = 0; c < NCLS; ++c) lab[k][c] = lr[c];
        }
        float votes[NCLS];
#pragma unroll
        for (int c = 0; c < NCLS; ++c) votes[c] = 0.f;
#pragma unroll
        for (int k = 0; k < KNN; ++k) {
            float ks = (kd[k] == 0.f) ? 1.f : kd[k];
#pragma unroll
            for (int c = 0; c < NCLS; ++c) votes[c] += lab[k][c] / ks;
        }
        int best = 0; float bv = votes[0];
#pragma unroll
        for (int c = 1; c < NCLS; ++c) { if (votes[c] > bv) { bv = votes[c]; best = c; } }
        bool zero_hit = (kd[0] == 0.f);
#pragma unroll
        for (int k = 0; k < KNN; ++k) out[(size_t)q * KNN + k] = kd[k];
        float* ro = out + (size_t)BQ * KNN + (size_t)q * NCLS;
#pragma unroll
        for (int c = 0; c < NCLS; ++c)
            ro[c] = zero_hit ? lab[0][c] : ((c == best) ? 1.f : 0.f);
    }
}

extern "C" void kernel_launch(void* const* d_in, const int* in_sizes, int n_in,
                              void* d_out, int out_size, void* d_ws, size_t ws_size,
                              hipStream_t stream) {
    const float* query  = (const float*)d_in[0];
    const float* train  = (const float*)d_in[1];
    const float* labels = (const float*)d_in[2];
    float* out = (float*)d_out;

    // ws layout:
    //   [0)       scale_u: 32 u32 (128 B)
    //   [128)     qs: 512*28 f32 {q_scaled[0..26], qn}
    //   [57472)   cand_d: 512*1024*3 f32
    //   [6348928) cand_i: 512*1024*3 i32   (total ~12.6 MB)
    char* ws = (char*)d_ws;
    unsigned* scale_u = (unsigned*)ws;
    float* qs     = (float*)(ws + 128);
    float* cand_d = (float*)(ws + 57472);
    int*   cand_i = (int*)(ws + 6348928);

    hipMemsetAsync(ws, 0, 128, stream);  // zero scale accumulators
    k_scale<<<SB, 256, 0, stream>>>(train, scale_u);
    k_qprep<<<2, 256, 0, stream>>>(query, scale_u, qs);
    k_pass1<<<G1, T1, 0, stream>>>(train, scale_u, qs, cand_d, cand_i);
    k_pass2<<<BQ, T2, 0, stream>>>(cand_d, cand_i, labels, out);
}